// Round 1
// baseline (143.985 us; speedup 1.0000x reference)
//
#include <hip/hip_runtime.h>
#include <math.h>

// JointAttentionMemoryBank via fp16 MFMA.  out = W @ softmax(W^T x / sqrt(D))
//   B=16 N=4096 D=128 M=1536.  fp32 in/out.
// R7: 2-phase stall fix (guide m233: phase-separated loops cap at ~28% MFMA util,
// matching R6's 31%). Sessions cut to 64 m (24 of them), Pbuf double-buffered,
// ONE barrier per session. Each inter-barrier segment runs phase2(q) || phase1(q+1):
// independent streams (32 MFMA + 8 glb loads + 24 ds_reads + 16 exp) that the
// compiler interleaves -> exp/VALU hides under MFMA, WT loads prefetch across
// phase2. LDS 36.9 KB keeps 4 blocks/CU (R5 lesson: avoid 3+1 rounds).
// exp2 folding: wt pre-scaled by log2e/sqrt(D) so softmax is raw v_exp_f32.
// No-max softmax (scaled logits ~N(0,1)), P unnormalized fp16, fp32 epilogue.

#define Bdim 16
#define Ndim 4096
#define Ddim 128
#define Mdim 1536
#define NT 64               // rows (n) per block
#define NTHREADS 256        // 4 waves
#define NSESS 24            // m-sessions (64 m each)
#define SESS_M 64
#define XPAD 136            // xs row stride fp16 (128+8)
#define PPAD 72             // Pbuf row stride fp16 (64+8)
#define NFRAG 24576         // fragments per W array = D*M/8

typedef __attribute__((ext_vector_type(8))) _Float16 f16x8;  // 4 VGPRs
typedef __attribute__((ext_vector_type(4))) _Float16 f16x4;  // 8 B
typedef __attribute__((ext_vector_type(4))) float    f32x4;  // MFMA C/D

// ---- prep: W (D,M) fp32 -> fragment-ordered fp16 arrays (gather form) ----
// wt (phase-1 A = W^T, pre-scaled log2e/sqrt(D) so exp(S)=exp2(S')):
//   frag f = (mt*4 + ks)*64 + lane ; m = mt*16 + (lane&15), d = ks*32 + (lane>>4)*8 + j
// wd (phase-2 A = W):
//   frag f = (dt*48 + km)*64 + lane ; d = dt*16 + (lane&15), m = km*32 + (lane>>4)*8 + j
__global__ void jamb_prep(const float* __restrict__ w,
                          _Float16* __restrict__ wt,
                          _Float16* __restrict__ wd) {
    const int tid = blockIdx.x * 256 + threadIdx.x;   // [0, 2*NFRAG)
    const float SC = 0.12751742957f;                  // log2(e)/sqrt(128)
    if (tid < NFRAG) {                                // blocks 0..95: wt
        const int f    = tid;
        const int lane = f & 63;
        const int fs   = f >> 6;
        const int ks   = fs & 3;          // 0..3
        const int mt   = fs >> 2;         // 0..95
        const int m    = mt * 16 + (lane & 15);
        const int d0   = ks * 32 + (lane >> 4) * 8;
        f16x8 pk;
        #pragma unroll
        for (int j = 0; j < 8; ++j)
            pk[j] = (_Float16)(w[(size_t)(d0 + j) * Mdim + m] * SC);
        *(f16x8*)&wt[(size_t)f * 8] = pk;
    } else {                                          // blocks 96..191: wd
        const int f    = tid - NFRAG;
        const int lane = f & 63;
        const int fs   = f >> 6;
        const int km   = fs % 48;         // 0..47
        const int dt   = fs / 48;         // 0..7
        const int d    = dt * 16 + (lane & 15);
        const int m0   = km * 32 + (lane >> 4) * 8;
        const float* src = w + (size_t)d * Mdim + m0;
        const float4 v0 = *(const float4*)src;
        const float4 v1 = *(const float4*)(src + 4);
        f16x8 pk;
        pk[0] = (_Float16)v0.x; pk[1] = (_Float16)v0.y;
        pk[2] = (_Float16)v0.z; pk[3] = (_Float16)v0.w;
        pk[4] = (_Float16)v1.x; pk[5] = (_Float16)v1.y;
        pk[6] = (_Float16)v1.z; pk[7] = (_Float16)v1.w;
        *(f16x8*)&wd[(size_t)f * 8] = pk;
    }
}

__global__ __launch_bounds__(NTHREADS, 4)
void jamb_mfma_kernel(const float* __restrict__ x,
                      const _Float16* __restrict__ wt,
                      const _Float16* __restrict__ wd,
                      float* __restrict__ out) {
    __shared__ __align__(16) _Float16 xs[NT * XPAD];       // 17408 B
    __shared__ __align__(16) _Float16 Pbuf[2][NT * PPAD];  // 18432 B (dbuf)
    __shared__ float redsum[4][4][16];                     // 1024 B  (total 36864 B)

    const int t    = threadIdx.x;
    const int w    = t >> 6;        // wave 0..3
    const int l    = t & 63;
    const int c16  = l & 15;
    const int quad = l >> 4;

    const int blk   = blockIdx.x;
    const int b     = blk >> 6;             // 64 blocks per batch
    const int nbase = (blk & 63) * NT;

    // ---- stage x tile -> LDS fp16 (coalesced float4 reads) ----
    {
        const float* xb = x + (size_t)(b * Ndim + nbase) * Ddim;
        #pragma unroll
        for (int i = 0; i < 8; ++i) {
            const int f   = t + i * 256;        // float4 index, [0,2048)
            const int row = f >> 5;             // 32 float4 per row
            const int c4  = (f & 31) * 4;
            const float4 v = *(const float4*)(xb + row * Ddim + c4);
            f16x4 pk;
            pk[0] = (_Float16)v.x; pk[1] = (_Float16)v.y;
            pk[2] = (_Float16)v.z; pk[3] = (_Float16)v.w;
            *(f16x4*)&xs[row * XPAD + c4] = pk;
        }
    }
    __syncthreads();

    const f16x8* WT = (const f16x8*)wt;
    const f16x8* WD = (const f16x8*)wd;

    float sums[4] = {0.f, 0.f, 0.f, 0.f};        // per n-tile unnormalized softmax sums
    f32x4 c[2][4];                               // phase-2 acc: 2 d-tiles x 4 n-tiles
    #pragma unroll
    for (int i = 0; i < 2; ++i)
        #pragma unroll
        for (int nt = 0; nt < 4; ++nt) c[i][nt] = (f32x4){0.f, 0.f, 0.f, 0.f};

    f16x8 fh[4];   // phase-1 A fragments (prefetched at segment top)

    // ---- phase-1 A-fragment loads for session `sess` (wave owns m-tile sess*4+w) ----
    auto p1load = [&](int sess) {
        const int mt = sess * 4 + w;
        #pragma unroll
        for (int s = 0; s < 4; ++s)
            fh[s] = WT[(mt * 4 + s) * 64 + l];
    };

    // ---- phase 1: S tile (1 m-tile x 4 n-tiles), exp, publish to Pbuf[sess&1] ----
    auto p1 = [&](int sess) {
        f32x4 acc[4];
        #pragma unroll
        for (int nt = 0; nt < 4; ++nt) acc[nt] = (f32x4){0.f, 0.f, 0.f, 0.f};
        #pragma unroll
        for (int s = 0; s < 4; ++s) {
            f16x8 bx[4];
            #pragma unroll
            for (int nt = 0; nt < 4; ++nt)
                bx[nt] = *(const f16x8*)&xs[(nt * 16 + c16) * XPAD + s * 32 + quad * 8];
            #pragma unroll
            for (int nt = 0; nt < 4; ++nt)
                acc[nt] = __builtin_amdgcn_mfma_f32_16x16x32_f16(fh[s], bx[nt], acc[nt], 0, 0, 0);
        }
        _Float16* Pw = &Pbuf[sess & 1][0];
        const int mloc = w * 16 + quad * 4;       // session-local m column (wave's tile)
        #pragma unroll
        for (int nt = 0; nt < 4; ++nt) {
            const float e0 = exp2f(acc[nt][0]);   // wt pre-scaled by log2e -> exp2 == exp
            const float e1 = exp2f(acc[nt][1]);
            const float e2 = exp2f(acc[nt][2]);
            const float e3 = exp2f(acc[nt][3]);
            sums[nt] += (e0 + e1) + (e2 + e3);
            f16x4 pk;
            pk[0] = (_Float16)e0; pk[1] = (_Float16)e1;
            pk[2] = (_Float16)e2; pk[3] = (_Float16)e3;
            *(f16x4*)&Pw[(nt * 16 + c16) * PPAD + mloc] = pk;
        }
    };

    // ---- phase 2: 2 m-ksteps over session q; wave owns d-tiles 2w, 2w+1 ----
    auto p2 = [&](int q) {
        const _Float16* Pr = &Pbuf[q & 1][0];
        #pragma unroll
        for (int sk = 0; sk < 2; ++sk) {
            const f16x8 a0 = WD[((2 * w)     * 48 + q * 2 + sk) * 64 + l];
            const f16x8 a1 = WD[((2 * w + 1) * 48 + q * 2 + sk) * 64 + l];
            f16x8 p[4];
            #pragma unroll
            for (int nt = 0; nt < 4; ++nt)
                p[nt] = *(const f16x8*)&Pr[(nt * 16 + c16) * PPAD + sk * 32 + quad * 8];
            #pragma unroll
            for (int nt = 0; nt < 4; ++nt) {
                c[0][nt] = __builtin_amdgcn_mfma_f32_16x16x32_f16(a0, p[nt], c[0][nt], 0, 0, 0);
                c[1][nt] = __builtin_amdgcn_mfma_f32_16x16x32_f16(a1, p[nt], c[1][nt], 0, 0, 0);
            }
        }
    };

    // ---- skewed pipeline: one barrier per session, phase2(q) || phase1(q+1) ----
    // Hazards: p1(q+1) writes buf[(q+1)&1], last read by p2(q-1) before this
    // barrier; p2(q) reads buf[q&1], written by p1(q) before this barrier. OK.
    p1load(0);
    p1(0);
    #pragma unroll 1
    for (int q = 0; q < NSESS - 1; ++q) {
        __syncthreads();           // publish P(q); retire reads of P(q-1)
        p1load(q + 1);             // issue WT loads first: hide L2 latency under p2
        p2(q);
        p1(q + 1);
    }
    __syncthreads();
    p2(NSESS - 1);

    // ---- softmax sums: cross-quad butterfly, cross-wave via LDS ----
    #pragma unroll
    for (int nt = 0; nt < 4; ++nt) {
        sums[nt] += __shfl_xor(sums[nt], 16, 64);
        sums[nt] += __shfl_xor(sums[nt], 32, 64);
    }
    if (quad == 0) {
        #pragma unroll
        for (int nt = 0; nt < 4; ++nt) redsum[w][nt][c16] = sums[nt];
    }
    __syncthreads();

    float inv[4];
    #pragma unroll
    for (int nt = 0; nt < 4; ++nt)
        inv[nt] = 1.f / ((redsum[0][nt][c16] + redsum[1][nt][c16]) +
                         (redsum[2][nt][c16] + redsum[3][nt][c16]));

    // ---- epilogue: C row = d-in-tile = quad*4+reg, col n = c16 ----
    #pragma unroll
    for (int dt2 = 0; dt2 < 2; ++dt2) {
        #pragma unroll
        for (int nt = 0; nt < 4; ++nt) {
            float* op = out + (size_t)(b * Ndim + nbase + nt * 16 + c16) * Ddim
                           + (2 * w + dt2) * 16 + quad * 4;
            float4 o;
            o.x = c[dt2][nt][0] * inv[nt];
            o.y = c[dt2][nt][1] * inv[nt];
            o.z = c[dt2][nt][2] * inv[nt];
            o.w = c[dt2][nt][3] * inv[nt];
            *(float4*)op = o;
        }
    }
}

extern "C" void kernel_launch(void* const* d_in, const int* in_sizes, int n_in,
                              void* d_out, int out_size, void* d_ws, size_t ws_size,
                              hipStream_t stream) {
    const float* x = (const float*)d_in[0];   // (B,N,D)
    const float* w = (const float*)d_in[1];   // (1,D,M)
    float* out = (float*)d_out;
    (void)in_sizes; (void)n_in; (void)out_size; (void)ws_size;

    _Float16* wt = (_Float16*)d_ws;           // 384 KB
    _Float16* wd = wt + Ddim * Mdim;          // 384 KB

    jamb_prep<<<dim3((2 * NFRAG) / 256), dim3(256), 0, stream>>>(w, wt, wd);  // 192 blocks
    jamb_mfma_kernel<<<dim3((Bdim * Ndim) / NT), dim3(NTHREADS), 0, stream>>>(x, wt, wd, out);
}